// Round 4
// baseline (108.795 us; speedup 1.0000x reference)
//
#include <hip/hip_runtime.h>

#define NOBJ   32
#define DIM    128
#define HW     256
#define R1     8192
#define NPAIR  262144
#define BN_EPS 1e-5f

typedef unsigned short u16;
typedef unsigned int   u32;
typedef __attribute__((ext_vector_type(8))) short bf16x8;
typedef __attribute__((ext_vector_type(4))) float f32x4;
typedef __attribute__((ext_vector_type(4))) unsigned short u16x4;
typedef __attribute__((ext_vector_type(4))) unsigned int u32x4;

__device__ __forceinline__ u16 f2bf(float f) {
    union { float f; unsigned u; } v; v.f = f;
    unsigned r = v.u + 0x7fffu + ((v.u >> 16) & 1u);
    return (u16)(r >> 16);
}
__device__ __forceinline__ float bf2f(u16 u) {
    union { unsigned u; float f; } v; v.u = ((unsigned)u) << 16; return v.f;
}
__device__ __forceinline__ u16x4 cvt4(float4 v) {
    u16x4 r;
    r[0] = f2bf(v.x); r[1] = f2bf(v.y); r[2] = f2bf(v.z); r[3] = f2bf(v.w);
    return r;
}

// ---------------------------------------------------------------------------
// convert + zero-init fused: state/weights fp32->bf16, zero agg/d_out/sums.
// W1b remapped [512][128]: row n<256 = w1[n][0:128], row n>=256 = w1[n-256][128:256].
// ---------------------------------------------------------------------------
__global__ __launch_bounds__(256) void convert_kernel(
    const float4* __restrict__ state, const float* __restrict__ w1,
    const float4* __restrict__ w2, const float4* __restrict__ fw1,
    const float4* __restrict__ fw2,
    u16x4* __restrict__ Ab, u16x4* __restrict__ W1b, u16x4* __restrict__ W2b,
    u16x4* __restrict__ FW1b, u16x4* __restrict__ FW2b,
    f32x4* __restrict__ agg, f32x4* __restrict__ dout, f32x4* __restrict__ sums)
{
    int g = blockIdx.x * 256 + threadIdx.x;
    if (g < 262144) { Ab[g] = cvt4(state[g]); return; }
    g -= 262144;
    if (g < 16384) {
        const int o = g * 4, n = o >> 7, k = o & 127;
        const float4 v = *(const float4*)(w1 + (n < 256 ? n * 256 + k
                                                        : (n - 256) * 256 + 128 + k));
        W1b[g] = cvt4(v); return;
    }
    g -= 16384;
    if (g < 8192) { W2b[g] = cvt4(w2[g]); return; }
    g -= 8192;
    if (g < 16384) { FW1b[g] = cvt4(fw1[g]); return; }
    g -= 16384;
    if (g < 8192) { FW2b[g] = cvt4(fw2[g]); return; }
    g -= 8192;
    const f32x4 z = {};
    if (g < 262144) { agg[g] = z; return; }
    g -= 262144;
    if (g < 262144) { dout[g] = z; return; }
    g -= 262144;
    if (g < 256) sums[g] = z;
}

// ---------------------------------------------------------------------------
// Unified bf16 MFMA GEMM. C = A @ W^T (+ bias). Wave = 16 rows x 64 cols,
// 4 waves/block = 64x64 tile. grid (N/64, M/64, SPLITK).
// AMODE: 0 = A bf16; 2 = A f32 with fused BN+lrelu+cvt (coeffs in ad[]).
// A2MODE: 1 = for kabs>=KSPLIT read A2 (f32, cvt inline, k rebased).
// OMODE: 1 = bf16 store; 2 = f32 atomicAdd (bias only at z==0);
//        3 = f32 store + fused column stats into stat_sums.
// ---------------------------------------------------------------------------
__device__ __forceinline__ bf16x8 cvt8_f32(const float* p) {
    f32x4 v0 = *(const f32x4*)p, v1 = *(const f32x4*)(p + 4);
    bf16x8 r;
    #pragma unroll
    for (int k = 0; k < 4; ++k) {
        r[k]     = (short)f2bf(v0[k]);
        r[4 + k] = (short)f2bf(v1[k]);
    }
    return r;
}
__device__ __forceinline__ bf16x8 cvt8_bn(const float* p, const float* a, const float* d) {
    f32x4 v0 = *(const f32x4*)p, v1 = *(const f32x4*)(p + 4);
    f32x4 a0 = *(const f32x4*)a, a1 = *(const f32x4*)(a + 4);
    f32x4 d0 = *(const f32x4*)d, d1 = *(const f32x4*)(d + 4);
    bf16x8 r;
    #pragma unroll
    for (int k = 0; k < 4; ++k) {
        float x0 = fmaf(a0[k], v0[k], d0[k]); x0 = fmaxf(x0, 0.01f * x0);
        float x1 = fmaf(a1[k], v1[k], d1[k]); x1 = fmaxf(x1, 0.01f * x1);
        r[k]     = (short)f2bf(x0);
        r[4 + k] = (short)f2bf(x1);
    }
    return r;
}

template<int KSTEPS, int KSPLIT, int AMODE, int A2MODE, int OMODE>
__global__ __launch_bounds__(256) void mfma_gemm(
    const void* __restrict__ A, int lda,
    const void* __restrict__ A2, int lda2,
    const u16* __restrict__ W, int ldw,
    const float* __restrict__ bias, float bias_scale,
    const float* __restrict__ ad,
    void* __restrict__ Cout, int ldc,
    float* __restrict__ stat_sums)
{
    __shared__ float sred[128];
    const int lane = threadIdx.x & 63;
    const int wave = threadIdx.x >> 6;
    const int row0 = blockIdx.y * 64 + wave * 16;
    const int col0 = blockIdx.x * 64;
    const int lr = lane & 15;
    const int lk = (lane >> 4) * 8;
    const int kbase = blockIdx.z * (KSTEPS * 32);

    f32x4 acc[4] = {};

    #pragma unroll
    for (int ks = 0; ks < KSTEPS; ++ks) {
        const int kabs = kbase + ks * 32 + lk;
        bf16x8 af;
        if (A2MODE == 1 && kabs >= KSPLIT) {
            af = cvt8_f32((const float*)A2 + (size_t)(row0 + lr) * lda2 + (kabs - KSPLIT));
        } else if (AMODE == 0) {
            af = *(const bf16x8*)((const u16*)A + (size_t)(row0 + lr) * lda + kabs);
        } else {
            af = cvt8_bn((const float*)A + (size_t)(row0 + lr) * lda + kabs,
                         ad + kabs, ad + 256 + kabs);
        }
        bf16x8 bf[4];
        #pragma unroll
        for (int cf = 0; cf < 4; ++cf)
            bf[cf] = *(const bf16x8*)(W + (size_t)(col0 + cf * 16 + lr) * ldw + kabs);
        #pragma unroll
        for (int cf = 0; cf < 4; ++cf)
            acc[cf] = __builtin_amdgcn_mfma_f32_16x16x32_bf16(af, bf[cf], acc[cf], 0, 0, 0);
    }

    if (OMODE == 3) {
        if (threadIdx.x < 128) sred[threadIdx.x] = 0.f;
        __syncthreads();
    }
    const bool addb = bias && (OMODE != 2 || blockIdx.z == 0);
    #pragma unroll
    for (int cf = 0; cf < 4; ++cf) {
        const int col = col0 + cf * 16 + lr;
        const float bv = addb ? bias_scale * bias[col] : 0.f;
        float s = 0.f, ss = 0.f;
        #pragma unroll
        for (int r = 0; r < 4; ++r) {
            const int row = row0 + (lane >> 4) * 4 + r;
            const float v = acc[cf][r] + bv;
            if (OMODE == 1) {
                ((u16*)Cout)[(size_t)row * ldc + col] = f2bf(v);
            } else if (OMODE == 2) {
                atomicAdd((float*)Cout + (size_t)row * ldc + col, v);
            } else {
                ((float*)Cout)[(size_t)row * ldc + col] = v;
                s += v;
                ss = fmaf(v, v, ss);
            }
        }
        if (OMODE == 3) {
            atomicAdd(&sred[cf * 16 + lr], s);
            atomicAdd(&sred[64 + cf * 16 + lr], ss);
        }
    }
    if (OMODE == 3) {
        __syncthreads();
        if (threadIdx.x < 64) {
            atomicAdd(&stat_sums[col0 + threadIdx.x], sred[threadIdx.x]);
            atomicAdd(&stat_sums[256 + col0 + threadIdx.x], sred[64 + threadIdx.x]);
        }
    }
}

// ---------------------------------------------------------------------------
// BN1 stats over implicit H1 = e*(P+Q)+b1; PQ is bf16 [8192][512].
// Grid (256 batches, 4 i-groups of 8). Lane owns 4 columns. Edge lists
// compacted via ballot; pads hit zero row 32, corrected closed-form.
// ---------------------------------------------------------------------------
__global__ __launch_bounds__(256) void stats1_kernel(
    const u16* __restrict__ PQb, const float* __restrict__ edges,
    const float* __restrict__ b1, float* __restrict__ sums)
{
    __shared__ u16 Qsb[33 * 256];                        // 16.5 KB, row 32 = 0
    __shared__ __align__(16) unsigned char list8[8 * 32];
    __shared__ int n1s[8];

    const int b    = blockIdx.x;
    const int i0   = blockIdx.y * 8;
    const int t    = threadIdx.x;
    const int lane = t & 63;
    const int w    = t >> 6;
    const int c0   = lane * 4;

    const u16* Qb = PQb + (size_t)b * (32 * 512) + 256;
    #pragma unroll
    for (int it = 0; it < 8; ++it) {
        const int row = w + it * 4;
        *(u16x4*)&Qsb[row * 256 + c0] = *(const u16x4*)(Qb + row * 512 + c0);
    }
    if (t < 64) { u16x4 z = {}; *(u16x4*)&Qsb[32 * 256 + t * 4] = z; }
    if (t < 64) ((u32*)list8)[t] = 0x20202020u;          // pad sentinel j=32

    const int il_t = t >> 5;
    const int j_t  = t & 31;
    const float ev = edges[(size_t)b * 1024 + (i0 + il_t) * 32 + j_t];
    const bool val = (ev != 0.f);
    __syncthreads();

    const unsigned long long bal = __ballot(val);
    const u32 m32 = (lane < 32) ? (u32)bal : (u32)(bal >> 32);
    if (val) list8[il_t * 32 + __popc(m32 & ((1u << j_t) - 1u))] = (unsigned char)j_t;
    if (j_t == 0) n1s[il_t] = __popc(m32);
    __syncthreads();

    const f32x4 bk = *(const f32x4*)(b1 + c0);
    f32x4 s4 = {}, ss4 = {};

    #pragma unroll
    for (int ii = 0; ii < 2; ++ii) {
        const int il = 2 * w + ii;
        const int i  = i0 + il;
        const int n1   = n1s[il];
        const int npad = (n1 + 3) & ~3;
        const u16x4 pu = *(const u16x4*)(PQb + (size_t)(b * 32 + i) * 512 + c0);
        f32x4 pb;
        #pragma unroll
        for (int k = 0; k < 4; ++k) pb[k] = bf2f(pu[k]) + bk[k];
        const float fz = (float)(32 - n1);
        const float fp = (float)(npad - n1);
        #pragma unroll
        for (int k = 0; k < 4; ++k) {
            s4[k]  += fz * bk[k] - fp * pb[k];
            ss4[k] += fz * bk[k] * bk[k] - fp * pb[k] * pb[k];
        }
        const u32x4 l0 = *(const u32x4*)(list8 + il * 32);
        const u32x4 l1 = *(const u32x4*)(list8 + il * 32 + 16);
        const u32 wbuf[8] = {l0[0], l0[1], l0[2], l0[3], l1[0], l1[1], l1[2], l1[3]};
        #pragma unroll
        for (int wi = 0; wi < 8; ++wi) {
            if (wi * 4 >= npad) break;
            const u32 w4 = wbuf[wi];
            #pragma unroll
            for (int kb = 0; kb < 4; ++kb) {
                const int j = (w4 >> (kb * 8)) & 0xff;
                const u16x4 qu = *(const u16x4*)&Qsb[j * 256 + c0];
                #pragma unroll
                for (int k = 0; k < 4; ++k) {
                    const float x = pb[k] + bf2f(qu[k]);
                    s4[k] += x;
                    ss4[k] = fmaf(x, x, ss4[k]);
                }
            }
        }
    }

    __syncthreads();
    float* red = (float*)Qsb;            // overlay reduction buffer (8 KB)
    *(f32x4*)(red + w * 256 + c0)        = s4;
    *(f32x4*)(red + 1024 + w * 256 + c0) = ss4;
    __syncthreads();
    float as = 0.f, ass = 0.f;
    #pragma unroll
    for (int ww = 0; ww < 4; ++ww) {
        as  += red[ww * 256 + t];
        ass += red[1024 + ww * 256 + t];
    }
    atomicAdd(&sums[t], as);
    atomicAdd(&sums[256 + t], ass);
}

// ---------------------------------------------------------------------------
// S[b,i,:] = sum_j lrelu(a*(P+Q)+d), finalize1 folded; bf16 out.
// ---------------------------------------------------------------------------
__global__ __launch_bounds__(256) void s_kernel(
    const u16* __restrict__ PQb, const float* __restrict__ edges,
    const float* __restrict__ sums, const float* __restrict__ gamma,
    const float* __restrict__ beta, const float* __restrict__ b1,
    u16* __restrict__ Sb)
{
    __shared__ u16 Qsb[33 * 256];
    __shared__ __align__(16) unsigned char list8[8 * 32];
    __shared__ int n1s[8];

    const int b    = blockIdx.x;
    const int i0   = blockIdx.y * 8;
    const int t    = threadIdx.x;
    const int lane = t & 63;
    const int w    = t >> 6;
    const int c0   = lane * 4;

    const float invN = 1.f / (float)NPAIR;
    const f32x4 s1  = *(const f32x4*)(sums + c0);
    const f32x4 s2  = *(const f32x4*)(sums + 256 + c0);
    const f32x4 g4  = *(const f32x4*)(gamma + c0);
    const f32x4 be4 = *(const f32x4*)(beta + c0);
    const f32x4 b14 = *(const f32x4*)(b1 + c0);
    f32x4 a4, d4, ld4;
    #pragma unroll
    for (int k = 0; k < 4; ++k) {
        const float mean = s1[k] * invN;
        const float var  = fmaf(-mean, mean, s2[k] * invN);
        a4[k]  = g4[k] * rsqrtf(var + BN_EPS);
        d4[k]  = fmaf(b14[k] - mean, a4[k], be4[k]);
        ld4[k] = fmaxf(d4[k], 0.01f * d4[k]);
    }

    const u16* Qb = PQb + (size_t)b * (32 * 512) + 256;
    #pragma unroll
    for (int it = 0; it < 8; ++it) {
        const int row = w + it * 4;
        *(u16x4*)&Qsb[row * 256 + c0] = *(const u16x4*)(Qb + row * 512 + c0);
    }
    if (t < 64) { u16x4 z = {}; *(u16x4*)&Qsb[32 * 256 + t * 4] = z; }
    if (t < 64) ((u32*)list8)[t] = 0x20202020u;

    const int il_t = t >> 5;
    const int j_t  = t & 31;
    const float ev = edges[(size_t)b * 1024 + (i0 + il_t) * 32 + j_t];
    const bool val = (ev != 0.f);
    __syncthreads();

    const unsigned long long bal = __ballot(val);
    const u32 m32 = (lane < 32) ? (u32)bal : (u32)(bal >> 32);
    if (val) list8[il_t * 32 + __popc(m32 & ((1u << j_t) - 1u))] = (unsigned char)j_t;
    if (j_t == 0) n1s[il_t] = __popc(m32);
    __syncthreads();

    #pragma unroll
    for (int ii = 0; ii < 2; ++ii) {
        const int il = 2 * w + ii;
        const int i  = i0 + il;
        const int n1   = n1s[il];
        const int npad = (n1 + 3) & ~3;
        const u16x4 pu = *(const u16x4*)(PQb + (size_t)(b * 32 + i) * 512 + c0);
        f32x4 ap, acc;
        const float fz = (float)(32 - n1);
        const float fp = (float)(npad - n1);
        #pragma unroll
        for (int k = 0; k < 4; ++k) {
            ap[k] = fmaf(a4[k], bf2f(pu[k]), d4[k]);
            const float lap = fmaxf(ap[k], 0.01f * ap[k]);
            acc[k] = fz * ld4[k] - fp * lap;
        }
        const u32x4 l0 = *(const u32x4*)(list8 + il * 32);
        const u32x4 l1 = *(const u32x4*)(list8 + il * 32 + 16);
        const u32 wbuf[8] = {l0[0], l0[1], l0[2], l0[3], l1[0], l1[1], l1[2], l1[3]};
        #pragma unroll
        for (int wi = 0; wi < 8; ++wi) {
            if (wi * 4 >= npad) break;
            const u32 w4 = wbuf[wi];
            #pragma unroll
            for (int kb = 0; kb < 4; ++kb) {
                const int j = (w4 >> (kb * 8)) & 0xff;
                const u16x4 qu = *(const u16x4*)&Qsb[j * 256 + c0];
                #pragma unroll
                for (int k = 0; k < 4; ++k) {
                    const float x = fmaf(a4[k], bf2f(qu[k]), ap[k]);
                    acc[k] += fmaxf(x, 0.01f * x);
                }
            }
        }
        u16x4 o;
        #pragma unroll
        for (int k = 0; k < 4; ++k) o[k] = f2bf(acc[k]);
        *(u16x4*)(Sb + (size_t)(b * 32 + i) * 256 + c0) = o;
    }
}

// BN2 coefficients from fused H2 stats.
__global__ void finalize2_kernel(const float* __restrict__ sums,
                                 const float* __restrict__ gamma,
                                 const float* __restrict__ beta,
                                 float* __restrict__ ad)
{
    const int t = threadIdx.x;
    const float invN = 1.f / (float)R1;
    const float mean = sums[t] * invN;
    const float var  = fmaf(-mean, mean, sums[HW + t] * invN);
    const float a    = gamma[t] * rsqrtf(var + BN_EPS);
    ad[t]       = a;
    ad[HW + t]  = fmaf(-mean, a, beta[t]);   // bias already inside H2
}

// ---------------------------------------------------------------------------
extern "C" void kernel_launch(void* const* d_in, const int* in_sizes, int n_in,
                              void* d_out, int out_size, void* d_ws, size_t ws_size,
                              hipStream_t stream)
{
    const float* state     = (const float*)d_in[0];
    const float* edges     = (const float*)d_in[1];
    const float* msg_w1    = (const float*)d_in[2];
    const float* msg_b1    = (const float*)d_in[3];
    const float* msg_gamma = (const float*)d_in[4];
    const float* msg_beta  = (const float*)d_in[5];
    const float* msg_w2    = (const float*)d_in[6];
    const float* msg_b2    = (const float*)d_in[7];
    const float* fin_w1    = (const float*)d_in[8];
    const float* fin_b1    = (const float*)d_in[9];
    const float* fin_gamma = (const float*)d_in[10];
    const float* fin_beta  = (const float*)d_in[11];
    const float* fin_w2    = (const float*)d_in[12];
    const float* fin_b2    = (const float*)d_in[13];

    char* w = (char*)d_ws;
    u16*   PQb  = (u16*)(w);                // 8192x512 bf16  ( 8 MB)
    float* H2   = (float*)(w + 8388608);    // 8192x256 f32   ( 8 MB)
    float* agg  = (float*)(w + 16777216);   // 8192x128 f32   ( 4 MB)
    u16*   Ab   = (u16*)(w + 20971520);     // 8192x128 bf16  ( 2 MB)
    u16*   Sb   = (u16*)(w + 23068672);     // 8192x256 bf16  ( 4 MB)
    u16*   W1b  = (u16*)(w + 27262976);     // 512x128 bf16
    u16*   W2b  = (u16*)(w + 27394048);     // 128x256 bf16
    u16*   FW1b = (u16*)(w + 27459584);     // 256x256 bf16
    u16*   FW2b = (u16*)(w + 27590656);     // 128x256 bf16
    float* sums = (float*)(w + 27656192);   // sums1(512) + sums2(512) + ad2(512)
    float* sums2 = sums + 512;
    float* ad2   = sums + 1024;

    // convert + zero agg/d_out/sums (3265 blocks)
    convert_kernel<<<3265, 256, 0, stream>>>(
        (const float4*)state, msg_w1, (const float4*)msg_w2,
        (const float4*)fin_w1, (const float4*)fin_w2,
        (u16x4*)Ab, (u16x4*)W1b, (u16x4*)W2b, (u16x4*)FW1b, (u16x4*)FW2b,
        (f32x4*)agg, (f32x4*)d_out, (f32x4*)sums);

    // PQ = state_b @ [w1a|w1b]^T  -> bf16 (M=8192, N=512, K=128)
    mfma_gemm<4, (1 << 30), 0, 0, 1><<<dim3(8, 128, 1), 256, 0, stream>>>(
        Ab, 128, nullptr, 0, W1b, 128, nullptr, 0.f, nullptr, PQb, 512, nullptr);

    stats1_kernel<<<dim3(256, 4), 256, 0, stream>>>(PQb, edges, msg_b1, sums);
    s_kernel<<<dim3(256, 4), 256, 0, stream>>>(PQb, edges, sums, msg_gamma,
                                               msg_beta, msg_b1, Sb);

    // agg = S @ w2^T + 32*b2  (split-K=2, fp32 atomic)
    mfma_gemm<4, (1 << 30), 0, 0, 2><<<dim3(2, 128, 2), 256, 0, stream>>>(
        Sb, 256, nullptr, 0, W2b, 256, msg_b2, (float)NOBJ, nullptr, agg, 128, nullptr);

    // H2 = [state_b | agg] @ fw1^T + fb1, fused column stats (M=8192,N=256,K=256)
    mfma_gemm<8, 128, 0, 1, 3><<<dim3(4, 128, 1), 256, 0, stream>>>(
        Ab, 128, agg, 128, FW1b, 256, fin_b1, 1.f, nullptr, H2, 256, sums2);

    finalize2_kernel<<<1, 256, 0, stream>>>(sums2, fin_gamma, fin_beta, ad2);

    // out = lrelu(bn(H2)) @ fw2^T + fb2  (BN fused into A-read, split-K=2)
    mfma_gemm<4, (1 << 30), 2, 0, 2><<<dim3(2, 128, 2), 256, 0, stream>>>(
        H2, 256, nullptr, 0, FW2b, 256, fin_b2, 1.f, ad2, d_out, 128, nullptr);
}

// Round 5
// 94.368 us; speedup vs baseline: 1.1529x; 1.1529x over previous
//
#include <hip/hip_runtime.h>

#define NOBJ   32
#define DIM    128
#define HW     256
#define R1     8192
#define NPAIR  262144
#define BN_EPS 1e-5f

typedef unsigned short u16;
typedef unsigned int   u32;
typedef __attribute__((ext_vector_type(8))) short bf16x8;
typedef __attribute__((ext_vector_type(4))) float f32x4;
typedef __attribute__((ext_vector_type(4))) unsigned short u16x4;
typedef __attribute__((ext_vector_type(4))) unsigned int u32x4;

__device__ __forceinline__ u16 f2bf(float f) {
    union { float f; unsigned u; } v; v.f = f;
    unsigned r = v.u + 0x7fffu + ((v.u >> 16) & 1u);
    return (u16)(r >> 16);
}
__device__ __forceinline__ float bf2f(u16 u) {
    union { unsigned u; float f; } v; v.u = ((unsigned)u) << 16; return v.f;
}
__device__ __forceinline__ u16x4 cvt4(float4 v) {
    u16x4 r;
    r[0] = f2bf(v.x); r[1] = f2bf(v.y); r[2] = f2bf(v.z); r[3] = f2bf(v.w);
    return r;
}
__device__ __forceinline__ bf16x8 cvt8_f32(const float* p) {
    f32x4 v0 = *(const f32x4*)p, v1 = *(const f32x4*)(p + 4);
    bf16x8 r;
    #pragma unroll
    for (int k = 0; k < 4; ++k) {
        r[k]     = (short)f2bf(v0[k]);
        r[4 + k] = (short)f2bf(v1[k]);
    }
    return r;
}
__device__ __forceinline__ bf16x8 cvt8_bn(const float* p, const float* a, const float* d) {
    f32x4 v0 = *(const f32x4*)p, v1 = *(const f32x4*)(p + 4);
    f32x4 a0 = *(const f32x4*)a, a1 = *(const f32x4*)(a + 4);
    f32x4 d0 = *(const f32x4*)d, d1 = *(const f32x4*)(d + 4);
    bf16x8 r;
    #pragma unroll
    for (int k = 0; k < 4; ++k) {
        float x0 = fmaf(a0[k], v0[k], d0[k]); x0 = fmaxf(x0, 0.01f * x0);
        float x1 = fmaf(a1[k], v1[k], d1[k]); x1 = fmaxf(x1, 0.01f * x1);
        r[k]     = (short)f2bf(x0);
        r[4 + k] = (short)f2bf(x1);
    }
    return r;
}

// ---------------------------------------------------------------------------
// prep: weights fp32->bf16 (W1b remapped [512][128]) + zero stats sums.
// ---------------------------------------------------------------------------
__global__ __launch_bounds__(256) void prep_kernel(
    const float* __restrict__ w1, const float4* __restrict__ w2,
    const float4* __restrict__ fw1, const float4* __restrict__ fw2,
    u16x4* __restrict__ W1b, u16x4* __restrict__ W2b,
    u16x4* __restrict__ FW1b, u16x4* __restrict__ FW2b,
    f32x4* __restrict__ sums)
{
    int g = blockIdx.x * 256 + threadIdx.x;
    if (g < 16384) {
        const int o = g * 4, n = o >> 7, k = o & 127;
        const float4 v = *(const float4*)(w1 + (n < 256 ? n * 256 + k
                                                        : (n - 256) * 256 + 128 + k));
        W1b[g] = cvt4(v); return;
    }
    g -= 16384;
    if (g < 8192) { W2b[g] = cvt4(w2[g]); return; }
    g -= 8192;
    if (g < 16384) { FW1b[g] = cvt4(fw1[g]); return; }
    g -= 16384;
    if (g < 8192) { FW2b[g] = cvt4(fw2[g]); return; }
    g -= 8192;
    if (g < 256) { const f32x4 z = {}; sums[g] = z; }
}

// ---------------------------------------------------------------------------
// PQ = state @ [w1a|w1b]^T -> bf16 (M=8192, N=512, K=128).
// A read f32 + cvt inline; col-block 0 emits Ab (state bf16) as side product.
// ---------------------------------------------------------------------------
__global__ __launch_bounds__(256) void pq_gemm(
    const float* __restrict__ state, const u16* __restrict__ W1b,
    u16* __restrict__ PQb, u16* __restrict__ Ab)
{
    const int lane = threadIdx.x & 63;
    const int wave = threadIdx.x >> 6;
    const int row0 = blockIdx.y * 64 + wave * 16;
    const int col0 = blockIdx.x * 64;
    const int lr = lane & 15;
    const int lk = (lane >> 4) * 8;

    f32x4 acc[4] = {};
    #pragma unroll
    for (int ks = 0; ks < 4; ++ks) {
        const int kabs = ks * 32 + lk;
        const bf16x8 af = cvt8_f32(state + (size_t)(row0 + lr) * 128 + kabs);
        if (blockIdx.x == 0)
            *(bf16x8*)(Ab + (size_t)(row0 + lr) * 128 + kabs) = af;
        #pragma unroll
        for (int cf = 0; cf < 4; ++cf) {
            const bf16x8 bf = *(const bf16x8*)(W1b + (size_t)(col0 + cf * 16 + lr) * 128 + kabs);
            acc[cf] = __builtin_amdgcn_mfma_f32_16x16x32_bf16(af, bf, acc[cf], 0, 0, 0);
        }
    }
    #pragma unroll
    for (int cf = 0; cf < 4; ++cf) {
        const int col = col0 + cf * 16 + lr;
        #pragma unroll
        for (int r = 0; r < 4; ++r) {
            const int row = row0 + (lane >> 4) * 4 + r;
            PQb[(size_t)row * 512 + col] = f2bf(acc[cf][r]);
        }
    }
}

// ---------------------------------------------------------------------------
// BN1 stats over implicit H1 = e*(P+Q)+b1; PQ bf16 [8192][512].
// ---------------------------------------------------------------------------
__global__ __launch_bounds__(256) void stats1_kernel(
    const u16* __restrict__ PQb, const float* __restrict__ edges,
    const float* __restrict__ b1, float* __restrict__ sums)
{
    __shared__ u16 Qsb[33 * 256];
    __shared__ __align__(16) unsigned char list8[8 * 32];
    __shared__ int n1s[8];

    const int b    = blockIdx.x;
    const int i0   = blockIdx.y * 8;
    const int t    = threadIdx.x;
    const int lane = t & 63;
    const int w    = t >> 6;
    const int c0   = lane * 4;

    const u16* Qb = PQb + (size_t)b * (32 * 512) + 256;
    #pragma unroll
    for (int it = 0; it < 8; ++it) {
        const int row = w + it * 4;
        *(u16x4*)&Qsb[row * 256 + c0] = *(const u16x4*)(Qb + row * 512 + c0);
    }
    if (t < 64) { u16x4 z = {}; *(u16x4*)&Qsb[32 * 256 + t * 4] = z; }
    if (t < 64) ((u32*)list8)[t] = 0x20202020u;

    const int il_t = t >> 5;
    const int j_t  = t & 31;
    const float ev = edges[(size_t)b * 1024 + (i0 + il_t) * 32 + j_t];
    const bool val = (ev != 0.f);
    __syncthreads();

    const unsigned long long bal = __ballot(val);
    const u32 m32 = (lane < 32) ? (u32)bal : (u32)(bal >> 32);
    if (val) list8[il_t * 32 + __popc(m32 & ((1u << j_t) - 1u))] = (unsigned char)j_t;
    if (j_t == 0) n1s[il_t] = __popc(m32);
    __syncthreads();

    const f32x4 bk = *(const f32x4*)(b1 + c0);
    f32x4 s4 = {}, ss4 = {};

    #pragma unroll
    for (int ii = 0; ii < 2; ++ii) {
        const int il = 2 * w + ii;
        const int i  = i0 + il;
        const int n1   = n1s[il];
        const int npad = (n1 + 3) & ~3;
        const u16x4 pu = *(const u16x4*)(PQb + (size_t)(b * 32 + i) * 512 + c0);
        f32x4 pb;
        #pragma unroll
        for (int k = 0; k < 4; ++k) pb[k] = bf2f(pu[k]) + bk[k];
        const float fz = (float)(32 - n1);
        const float fp = (float)(npad - n1);
        #pragma unroll
        for (int k = 0; k < 4; ++k) {
            s4[k]  += fz * bk[k] - fp * pb[k];
            ss4[k] += fz * bk[k] * bk[k] - fp * pb[k] * pb[k];
        }
        const u32x4 l0 = *(const u32x4*)(list8 + il * 32);
        const u32x4 l1 = *(const u32x4*)(list8 + il * 32 + 16);
        const u32 wbuf[8] = {l0[0], l0[1], l0[2], l0[3], l1[0], l1[1], l1[2], l1[3]};
        #pragma unroll
        for (int wi = 0; wi < 8; ++wi) {
            if (wi * 4 >= npad) break;
            const u32 w4 = wbuf[wi];
            #pragma unroll
            for (int kb = 0; kb < 4; ++kb) {
                const int j = (w4 >> (kb * 8)) & 0xff;
                const u16x4 qu = *(const u16x4*)&Qsb[j * 256 + c0];
                #pragma unroll
                for (int k = 0; k < 4; ++k) {
                    const float x = pb[k] + bf2f(qu[k]);
                    s4[k] += x;
                    ss4[k] = fmaf(x, x, ss4[k]);
                }
            }
        }
    }

    __syncthreads();
    float* red = (float*)Qsb;
    *(f32x4*)(red + w * 256 + c0)        = s4;
    *(f32x4*)(red + 1024 + w * 256 + c0) = ss4;
    __syncthreads();
    float as = 0.f, ass = 0.f;
    #pragma unroll
    for (int ww = 0; ww < 4; ++ww) {
        as  += red[ww * 256 + t];
        ass += red[1024 + ww * 256 + t];
    }
    atomicAdd(&sums[t], as);
    atomicAdd(&sums[256 + t], ass);
}

// ---------------------------------------------------------------------------
// S-tile (16 rows) + fused agg GEMM: agg[16x128] = S[16x256] @ w2^T + 32*b2.
// S kept in XOR-swizzled LDS; grid (256 batches, 2 row-groups).
// ---------------------------------------------------------------------------
__global__ __launch_bounds__(256) void s_agg_kernel(
    const u16* __restrict__ PQb, const float* __restrict__ edges,
    const float* __restrict__ sums, const float* __restrict__ gamma,
    const float* __restrict__ beta, const float* __restrict__ b1,
    const u16* __restrict__ W2b, const float* __restrict__ b2,
    u16* __restrict__ aggb)
{
    __shared__ u16 Qsb[33 * 256];                 // 16.5 KB
    __shared__ u16 Ssb[16 * 256];                 // 8 KB, row-XOR swizzled
    __shared__ __align__(16) unsigned char list8[16 * 32];
    __shared__ int n1s[16];

    const int b    = blockIdx.x;
    const int i0   = blockIdx.y * 16;
    const int t    = threadIdx.x;
    const int lane = t & 63;
    const int w    = t >> 6;
    const int lr   = lane & 15;
    const int lk   = (lane >> 4) * 8;
    const int c0   = lane * 4;

    // BN1 coefficients for my 4 columns
    const float invN = 1.f / (float)NPAIR;
    const f32x4 s1  = *(const f32x4*)(sums + c0);
    const f32x4 s2  = *(const f32x4*)(sums + 256 + c0);
    const f32x4 g4  = *(const f32x4*)(gamma + c0);
    const f32x4 be4 = *(const f32x4*)(beta + c0);
    const f32x4 b14 = *(const f32x4*)(b1 + c0);
    f32x4 a4, d4, ld4;
    #pragma unroll
    for (int k = 0; k < 4; ++k) {
        const float mean = s1[k] * invN;
        const float var  = fmaf(-mean, mean, s2[k] * invN);
        a4[k]  = g4[k] * rsqrtf(var + BN_EPS);
        d4[k]  = fmaf(b14[k] - mean, a4[k], be4[k]);
        ld4[k] = fmaxf(d4[k], 0.01f * d4[k]);
    }

    // stage Q (all 32 rows of this batch)
    const u16* Qb = PQb + (size_t)b * (32 * 512) + 256;
    #pragma unroll
    for (int it = 0; it < 8; ++it) {
        const int row = w + it * 4;
        *(u16x4*)&Qsb[row * 256 + c0] = *(const u16x4*)(Qb + row * 512 + c0);
    }
    if (t < 64) { u16x4 z = {}; *(u16x4*)&Qsb[32 * 256 + t * 4] = z; }
    if (t < 128) ((u32*)list8)[t] = 0x20202020u;

    const int il_t = t >> 5;
    const int j_t  = t & 31;
    const float ev0 = edges[(size_t)b * 1024 + (i0 + il_t) * 32 + j_t];
    const float ev1 = edges[(size_t)b * 1024 + (i0 + 8 + il_t) * 32 + j_t];
    __syncthreads();

    {
        const unsigned long long bal0 = __ballot(ev0 != 0.f);
        const u32 m0 = (lane < 32) ? (u32)bal0 : (u32)(bal0 >> 32);
        if (ev0 != 0.f)
            list8[il_t * 32 + __popc(m0 & ((1u << j_t) - 1u))] = (unsigned char)j_t;
        if (j_t == 0) n1s[il_t] = __popc(m0);
        const unsigned long long bal1 = __ballot(ev1 != 0.f);
        const u32 m1 = (lane < 32) ? (u32)bal1 : (u32)(bal1 >> 32);
        if (ev1 != 0.f)
            list8[(8 + il_t) * 32 + __popc(m1 & ((1u << j_t) - 1u))] = (unsigned char)j_t;
        if (j_t == 0) n1s[8 + il_t] = __popc(m1);
    }
    __syncthreads();

    // pair-enumeration: wave w owns rows 4w..4w+3
    #pragma unroll
    for (int ii = 0; ii < 4; ++ii) {
        const int il = 4 * w + ii;
        const int i  = i0 + il;
        const int n1   = n1s[il];
        const int npad = (n1 + 3) & ~3;
        const u16x4 pu = *(const u16x4*)(PQb + (size_t)(b * 32 + i) * 512 + c0);
        f32x4 ap, acc;
        const float fz = (float)(32 - n1);
        const float fp = (float)(npad - n1);
        #pragma unroll
        for (int k = 0; k < 4; ++k) {
            ap[k] = fmaf(a4[k], bf2f(pu[k]), d4[k]);
            const float lap = fmaxf(ap[k], 0.01f * ap[k]);
            acc[k] = fz * ld4[k] - fp * lap;
        }
        const u32x4 l0 = *(const u32x4*)(list8 + il * 32);
        const u32x4 l1 = *(const u32x4*)(list8 + il * 32 + 16);
        const u32 wbuf[8] = {l0[0], l0[1], l0[2], l0[3], l1[0], l1[1], l1[2], l1[3]};
        #pragma unroll
        for (int wi = 0; wi < 8; ++wi) {
            if (wi * 4 >= npad) break;
            const u32 w4 = wbuf[wi];
            #pragma unroll
            for (int kb = 0; kb < 4; ++kb) {
                const int j = (w4 >> (kb * 8)) & 0xff;
                const u16x4 qu = *(const u16x4*)&Qsb[j * 256 + c0];
                #pragma unroll
                for (int k = 0; k < 4; ++k) {
                    const float x = fmaf(a4[k], bf2f(qu[k]), ap[k]);
                    acc[k] += fmaxf(x, 0.01f * x);
                }
            }
        }
        u16x4 o;
        #pragma unroll
        for (int k = 0; k < 4; ++k) o[k] = f2bf(acc[k]);
        // swizzled store: logical byte (lane*8) of row il
        const int off = (lane * 8) ^ ((il & 7) << 4);
        *(u16x4*)((char*)Ssb + il * 512 + off) = o;
    }
    __syncthreads();

    // agg tail: agg[16x128] = S @ w2^T + 32*b2 ; wave w covers 32 cols
    const int colw = w * 32;
    f32x4 acc2[2] = {};
    #pragma unroll
    for (int ks = 0; ks < 8; ++ks) {
        const int rdoff = (ks * 64 + (lane >> 4) * 16) ^ ((lr & 7) << 4);
        const bf16x8 afr = *(const bf16x8*)((const char*)Ssb + lr * 512 + rdoff);
        #pragma unroll
        for (int cf = 0; cf < 2; ++cf) {
            const bf16x8 bfr = *(const bf16x8*)(W2b + (size_t)(colw + cf * 16 + lr) * 256 + ks * 32 + lk);
            acc2[cf] = __builtin_amdgcn_mfma_f32_16x16x32_bf16(afr, bfr, acc2[cf], 0, 0, 0);
        }
    }
    #pragma unroll
    for (int cf = 0; cf < 2; ++cf) {
        const int col = colw + cf * 16 + lr;
        const float bv = (float)NOBJ * b2[col];
        #pragma unroll
        for (int r = 0; r < 4; ++r) {
            const int rowl = (lane >> 4) * 4 + r;
            aggb[(size_t)(b * 32 + i0 + rowl) * 128 + col] = f2bf(acc2[cf][r] + bv);
        }
    }
}

// ---------------------------------------------------------------------------
// H2 = [Ab | aggb] @ fw1^T + fb1 (f32 out) + fused column stats.
// Block 64 rows x 32 cols, grid (8, 128).
// ---------------------------------------------------------------------------
__global__ __launch_bounds__(256) void h2_gemm(
    const u16* __restrict__ Ab, const u16* __restrict__ aggb,
    const u16* __restrict__ FW1b, const float* __restrict__ fb1,
    float* __restrict__ H2, float* __restrict__ sums2)
{
    __shared__ float sred[64];
    const int lane = threadIdx.x & 63;
    const int wave = threadIdx.x >> 6;
    const int row0 = blockIdx.y * 64 + wave * 16;
    const int col0 = blockIdx.x * 32;
    const int lr = lane & 15;
    const int lk = (lane >> 4) * 8;

    f32x4 acc[2] = {};
    #pragma unroll
    for (int ks = 0; ks < 8; ++ks) {
        const int kabs = ks * 32 + lk;
        const bf16x8 af = (kabs < 128)
            ? *(const bf16x8*)(Ab   + (size_t)(row0 + lr) * 128 + kabs)
            : *(const bf16x8*)(aggb + (size_t)(row0 + lr) * 128 + (kabs - 128));
        #pragma unroll
        for (int cf = 0; cf < 2; ++cf) {
            const bf16x8 bf = *(const bf16x8*)(FW1b + (size_t)(col0 + cf * 16 + lr) * 256 + kabs);
            acc[cf] = __builtin_amdgcn_mfma_f32_16x16x32_bf16(af, bf, acc[cf], 0, 0, 0);
        }
    }

    if (threadIdx.x < 64) sred[threadIdx.x] = 0.f;
    __syncthreads();
    #pragma unroll
    for (int cf = 0; cf < 2; ++cf) {
        const int col = col0 + cf * 16 + lr;
        const float bv = fb1[col];
        float s = 0.f, ss = 0.f;
        #pragma unroll
        for (int r = 0; r < 4; ++r) {
            const int row = row0 + (lane >> 4) * 4 + r;
            const float v = acc[cf][r] + bv;
            H2[(size_t)row * 256 + col] = v;
            s += v;
            ss = fmaf(v, v, ss);
        }
        atomicAdd(&sred[cf * 16 + lr], s);
        atomicAdd(&sred[32 + cf * 16 + lr], ss);
    }
    __syncthreads();
    if (threadIdx.x < 32) {
        atomicAdd(&sums2[col0 + threadIdx.x], sred[threadIdx.x]);
        atomicAdd(&sums2[256 + col0 + threadIdx.x], sred[32 + threadIdx.x]);
    }
}

// ---------------------------------------------------------------------------
// out = lrelu(bn(H2)) @ fw2^T + fb2, finalize2 computed in-block.
// Block 64 rows x 32 cols, grid (4, 128).
// ---------------------------------------------------------------------------
__global__ __launch_bounds__(256) void out_gemm(
    const float* __restrict__ H2, const u16* __restrict__ FW2b,
    const float* __restrict__ fb2, const float* __restrict__ sums2,
    const float* __restrict__ gamma, const float* __restrict__ beta,
    float* __restrict__ out)
{
    __shared__ float adl[512];
    const int t = threadIdx.x;
    {
        const float invN = 1.f / (float)R1;
        const float mean = sums2[t] * invN;
        const float var  = fmaf(-mean, mean, sums2[256 + t] * invN);
        const float a    = gamma[t] * rsqrtf(var + BN_EPS);
        adl[t]       = a;
        adl[256 + t] = fmaf(-mean, a, beta[t]);
    }
    __syncthreads();

    const int lane = t & 63;
    const int wave = t >> 6;
    const int row0 = blockIdx.y * 64 + wave * 16;
    const int col0 = blockIdx.x * 32;
    const int lr = lane & 15;
    const int lk = (lane >> 4) * 8;

    f32x4 acc[2] = {};
    #pragma unroll
    for (int ks = 0; ks < 8; ++ks) {
        const int kabs = ks * 32 + lk;
        const bf16x8 af = cvt8_bn(H2 + (size_t)(row0 + lr) * 256 + kabs,
                                  adl + kabs, adl + 256 + kabs);
        #pragma unroll
        for (int cf = 0; cf < 2; ++cf) {
            const bf16x8 bf = *(const bf16x8*)(FW2b + (size_t)(col0 + cf * 16 + lr) * 256 + kabs);
            acc[cf] = __builtin_amdgcn_mfma_f32_16x16x32_bf16(af, bf, acc[cf], 0, 0, 0);
        }
    }
    #pragma unroll
    for (int cf = 0; cf < 2; ++cf) {
        const int col = col0 + cf * 16 + lr;
        const float bv = fb2[col];
        #pragma unroll
        for (int r = 0; r < 4; ++r) {
            const int row = row0 + (lane >> 4) * 4 + r;
            out[(size_t)row * 128 + col] = acc[cf][r] + bv;
        }
    }
}

// ---------------------------------------------------------------------------
extern "C" void kernel_launch(void* const* d_in, const int* in_sizes, int n_in,
                              void* d_out, int out_size, void* d_ws, size_t ws_size,
                              hipStream_t stream)
{
    const float* state     = (const float*)d_in[0];
    const float* edges     = (const float*)d_in[1];
    const float* msg_w1    = (const float*)d_in[2];
    const float* msg_b1    = (const float*)d_in[3];
    const float* msg_gamma = (const float*)d_in[4];
    const float* msg_beta  = (const float*)d_in[5];
    const float* msg_w2    = (const float*)d_in[6];
    const float* msg_b2    = (const float*)d_in[7];
    const float* fin_w1    = (const float*)d_in[8];
    const float* fin_b1    = (const float*)d_in[9];
    const float* fin_gamma = (const float*)d_in[10];
    const float* fin_beta  = (const float*)d_in[11];
    const float* fin_w2    = (const float*)d_in[12];
    const float* fin_b2    = (const float*)d_in[13];

    char* w = (char*)d_ws;
    u16*   PQb  = (u16*)(w);                // 8192x512 bf16  ( 8 MB)
    u16*   Ab   = (u16*)(w + 8388608);      // 8192x128 bf16  ( 2 MB)
    u16*   aggb = (u16*)(w + 10485760);     // 8192x128 bf16  ( 2 MB)
    float* H2   = (float*)(w + 12582912);   // 8192x256 f32   ( 8 MB)
    u16*   W1b  = (u16*)(w + 20971520);     // 512x128 bf16
    u16*   W2b  = (u16*)(w + 21102592);     // 128x256 bf16
    u16*   FW1b = (u16*)(w + 21168128);     // 256x256 bf16
    u16*   FW2b = (u16*)(w + 21299200);     // 128x256 bf16
    float* sums = (float*)(w + 21364736);   // sums1(512) + sums2(512)
    float* sums2 = sums + 512;

    prep_kernel<<<194, 256, 0, stream>>>(
        msg_w1, (const float4*)msg_w2, (const float4*)fin_w1, (const float4*)fin_w2,
        (u16x4*)W1b, (u16x4*)W2b, (u16x4*)FW1b, (u16x4*)FW2b, (f32x4*)sums);

    pq_gemm<<<dim3(8, 128), 256, 0, stream>>>(state, W1b, PQb, Ab);

    stats1_kernel<<<dim3(256, 4), 256, 0, stream>>>(PQb, edges, msg_b1, sums);

    s_agg_kernel<<<dim3(256, 2), 256, 0, stream>>>(
        PQb, edges, sums, msg_gamma, msg_beta, msg_b1, W2b, msg_b2, aggb);

    h2_gemm<<<dim3(8, 128), 256, 0, stream>>>(Ab, aggb, FW1b, fin_b1, H2, sums2);

    out_gemm<<<dim3(4, 128), 256, 0, stream>>>(
        H2, FW2b, fin_b2, sums2, fin_gamma, fin_beta, (float*)d_out);
}

// Round 6
// 69.387 us; speedup vs baseline: 1.5680x; 1.3600x over previous
//
#include <hip/hip_runtime.h>

#define NOBJ   32
#define DIM    128
#define HW     256
#define R1     8192
#define NPAIR  262144
#define BN_EPS 1e-5f

typedef unsigned short u16;
typedef unsigned int   u32;
typedef __attribute__((ext_vector_type(8))) short bf16x8;
typedef __attribute__((ext_vector_type(4))) float f32x4;
typedef __attribute__((ext_vector_type(4))) unsigned short u16x4;
typedef __attribute__((ext_vector_type(4))) unsigned int u32x4;

__device__ __forceinline__ u16 f2bf(float f) {
    union { float f; unsigned u; } v; v.f = f;
    unsigned r = v.u + 0x7fffu + ((v.u >> 16) & 1u);
    return (u16)(r >> 16);
}
__device__ __forceinline__ float bf2f(u16 u) {
    union { unsigned u; float f; } v; v.u = ((unsigned)u) << 16; return v.f;
}
__device__ __forceinline__ u16x4 cvt4(float4 v) {
    u16x4 r;
    r[0] = f2bf(v.x); r[1] = f2bf(v.y); r[2] = f2bf(v.z); r[3] = f2bf(v.w);
    return r;
}
__device__ __forceinline__ bf16x8 cvt8_f32(const float* p) {
    f32x4 v0 = *(const f32x4*)p, v1 = *(const f32x4*)(p + 4);
    bf16x8 r;
    #pragma unroll
    for (int k = 0; k < 4; ++k) {
        r[k]     = (short)f2bf(v0[k]);
        r[4 + k] = (short)f2bf(v1[k]);
    }
    return r;
}
__device__ __forceinline__ bf16x8 cvt8_bn(const float* p, const float* a, const float* d) {
    f32x4 v0 = *(const f32x4*)p, v1 = *(const f32x4*)(p + 4);
    f32x4 a0 = *(const f32x4*)a, a1 = *(const f32x4*)(a + 4);
    f32x4 d0 = *(const f32x4*)d, d1 = *(const f32x4*)(d + 4);
    bf16x8 r;
    #pragma unroll
    for (int k = 0; k < 4; ++k) {
        float x0 = fmaf(a0[k], v0[k], d0[k]); x0 = fmaxf(x0, 0.01f * x0);
        float x1 = fmaf(a1[k], v1[k], d1[k]); x1 = fmaxf(x1, 0.01f * x1);
        r[k]     = (short)f2bf(x0);
        r[4 + k] = (short)f2bf(x1);
    }
    return r;
}

// ---------------------------------------------------------------------------
// prep: weights fp32->bf16 (W1b remapped [512][128]) + zero sums region.
// ---------------------------------------------------------------------------
__global__ __launch_bounds__(256) void prep_kernel(
    const float* __restrict__ w1, const float4* __restrict__ w2,
    const float4* __restrict__ fw1, const float4* __restrict__ fw2,
    u16x4* __restrict__ W1b, u16x4* __restrict__ W2b,
    u16x4* __restrict__ FW1b, u16x4* __restrict__ FW2b,
    f32x4* __restrict__ sums)
{
    int g = blockIdx.x * 256 + threadIdx.x;
    if (g < 16384) {
        const int o = g * 4, n = o >> 7, k = o & 127;
        const float4 v = *(const float4*)(w1 + (n < 256 ? n * 256 + k
                                                        : (n - 256) * 256 + 128 + k));
        W1b[g] = cvt4(v); return;
    }
    g -= 16384;
    if (g < 8192) { W2b[g] = cvt4(w2[g]); return; }
    g -= 8192;
    if (g < 16384) { FW1b[g] = cvt4(fw1[g]); return; }
    g -= 16384;
    if (g < 8192) { FW2b[g] = cvt4(fw2[g]); return; }
    g -= 8192;
    if (g < 264) { const f32x4 z = {}; sums[g] = z; }
}

// ---------------------------------------------------------------------------
// Per-batch fused kernel (512 threads):
//   PQ[32x512] = state @ [w1a|w1b]^T via MFMA  -> PQb bf16 (+ Ab side-product)
//   EQ_i = sum_{j: e_ij=1} Q_j  (f32, -> EQf global)
//   BN1 stats (analytic): sumA = SUM rd*pb + eq ; sumB = SUM rd*pb^2 + 2 pb eq
//                         + SUM_j cd_j Q_j^2 ;  E_total -> sums[512]
// ---------------------------------------------------------------------------
__global__ __launch_bounds__(512) void pq_stats(
    const float* __restrict__ state, const u16* __restrict__ W1b,
    const float* __restrict__ edges, const float* __restrict__ b1,
    u16* __restrict__ PQb, u16* __restrict__ Ab, float* __restrict__ EQf,
    float* __restrict__ sums)
{
    __shared__ float Pls[32 * 256];                 // 32 KB rounded P
    __shared__ float Qls[33 * 256];                 // 33 KB rounded Q (row32=0)
    __shared__ float redA[8 * 256];                 // 8 KB
    __shared__ float redB[8 * 256];                 // 8 KB
    __shared__ u32 masks[32];
    __shared__ __align__(16) unsigned char list8[32 * 32];
    __shared__ float cdf[32];

    const int b    = blockIdx.x;
    const int t    = threadIdx.x;
    const int lane = t & 63;
    const int w    = t >> 6;       // 0..7
    const int lr   = lane & 15;
    const int lk   = (lane >> 4) * 8;
    const int c0   = lane * 4;

    if (t < 256) ((u32*)list8)[t] = 0x20202020u;    // pad sentinel j=32
    if (t < 64) { const f32x4 z = {}; *(f32x4*)&Qls[32 * 256 + t * 4] = z; }

    // edge values (registers; ballots later)
    const int il_t = t >> 5;       // 0..15
    const int j_t  = t & 31;
    const float ev0 = edges[(size_t)b * 1024 + il_t * 32 + j_t];
    const float ev1 = edges[(size_t)b * 1024 + (il_t + 16) * 32 + j_t];

    // ---- GEMM: this batch's PQ (wave w covers cols w*64..w*64+63) ----
    const int col0 = w * 64;
    f32x4 acc[2][4] = {};
    #pragma unroll
    for (int ks = 0; ks < 4; ++ks) {
        const int kabs = ks * 32 + lk;
        bf16x8 af[2];
        #pragma unroll
        for (int rf = 0; rf < 2; ++rf)
            af[rf] = cvt8_f32(state + (size_t)(b * 32 + rf * 16 + lr) * 128 + kabs);
        if (w == 0) {
            #pragma unroll
            for (int rf = 0; rf < 2; ++rf)
                *(bf16x8*)(Ab + (size_t)(b * 32 + rf * 16 + lr) * 128 + kabs) = af[rf];
        }
        #pragma unroll
        for (int cf = 0; cf < 4; ++cf) {
            const bf16x8 bf = *(const bf16x8*)(W1b + (size_t)(col0 + cf * 16 + lr) * 128 + kabs);
            #pragma unroll
            for (int rf = 0; rf < 2; ++rf)
                acc[rf][cf] = __builtin_amdgcn_mfma_f32_16x16x32_bf16(af[rf], bf, acc[rf][cf], 0, 0, 0);
        }
    }
    #pragma unroll
    for (int rf = 0; rf < 2; ++rf)
        #pragma unroll
        for (int cf = 0; cf < 4; ++cf) {
            const int col = col0 + cf * 16 + lr;
            #pragma unroll
            for (int r = 0; r < 4; ++r) {
                const int row = rf * 16 + (lane >> 4) * 4 + r;
                const u16 u = f2bf(acc[rf][cf][r]);
                PQb[(size_t)(b * 32 + row) * 512 + col] = u;
                const float fv = bf2f(u);
                if (w < 4) Pls[row * 256 + col]         = fv;
                else       Qls[row * 256 + (col - 256)] = fv;
            }
        }
    __syncthreads();   // S1: staging + inits visible

    // ---- masks + compacted lists ----
    {
        const unsigned long long bal0 = __ballot(ev0 != 0.f);
        const u32 m0 = (lane < 32) ? (u32)bal0 : (u32)(bal0 >> 32);
        if (ev0 != 0.f)
            list8[il_t * 32 + __popc(m0 & ((1u << j_t) - 1u))] = (unsigned char)j_t;
        if (j_t == 0) masks[il_t] = m0;
        const unsigned long long bal1 = __ballot(ev1 != 0.f);
        const u32 m1 = (lane < 32) ? (u32)bal1 : (u32)(bal1 >> 32);
        if (ev1 != 0.f)
            list8[(il_t + 16) * 32 + __popc(m1 & ((1u << j_t) - 1u))] = (unsigned char)j_t;
        if (j_t == 0) masks[il_t + 16] = m1;
    }
    __syncthreads();   // S2: masks + lists ready

    if (t < 32) {
        u32 cnt = 0;
        #pragma unroll
        for (int i = 0; i < 32; ++i) cnt += (masks[i] >> t) & 1u;
        cdf[t] = (float)cnt;
    }
    if (t == 0) {
        int tot = 0;
        #pragma unroll
        for (int i = 0; i < 32; ++i) tot += __popc(masks[i]);
        atomicAdd(&sums[512], (float)tot);
    }

    const f32x4 b14 = *(const f32x4*)(b1 + c0);
    f32x4 sumA = {}, sumB = {};

    // ---- EQ + row-terms: wave w owns rows 4w..4w+3 ----
    #pragma unroll
    for (int ii = 0; ii < 4; ++ii) {
        const int il = w * 4 + ii;
        const int n1 = __popc(masks[il]);
        const int npad = (n1 + 3) & ~3;
        const float frd = (float)n1;
        f32x4 eq = {};
        const u32x4 l0 = *(const u32x4*)(list8 + il * 32);
        const u32x4 l1 = *(const u32x4*)(list8 + il * 32 + 16);
        const u32 wbuf[8] = {l0[0], l0[1], l0[2], l0[3], l1[0], l1[1], l1[2], l1[3]};
        #pragma unroll
        for (int wi = 0; wi < 8; ++wi) {
            if (wi * 4 >= npad) break;
            const u32 w4 = wbuf[wi];
            #pragma unroll
            for (int kb = 0; kb < 4; ++kb) {
                const int j = (w4 >> (kb * 8)) & 0xff;          // pads -> row 32 (zero)
                const f32x4 q = *(const f32x4*)&Qls[j * 256 + c0];
                #pragma unroll
                for (int k = 0; k < 4; ++k) eq[k] += q[k];
            }
        }
        *(f32x4*)(EQf + (size_t)(b * 32 + il) * 256 + c0) = eq;
        const f32x4 p4 = *(const f32x4*)&Pls[il * 256 + c0];
        #pragma unroll
        for (int k = 0; k < 4; ++k) {
            const float pb = p4[k] + b14[k];
            sumA[k] += frd * pb + eq[k];
            sumB[k] = fmaf(frd * pb + 2.f * eq[k], pb, sumB[k]);
        }
    }
    __syncthreads();   // S3: cdf ready

    // ---- coldeg-weighted Q^2 (js split across waves) ----
    #pragma unroll
    for (int jj = 0; jj < 4; ++jj) {
        const int j = w * 4 + jj;
        const float cdj = cdf[j];
        const f32x4 q = *(const f32x4*)&Qls[j * 256 + c0];
        #pragma unroll
        for (int k = 0; k < 4; ++k) sumB[k] = fmaf(cdj * q[k], q[k], sumB[k]);
    }
    *(f32x4*)&redA[w * 256 + c0] = sumA;
    *(f32x4*)&redB[w * 256 + c0] = sumB;
    __syncthreads();   // S4
    if (t < 256) {
        float a = 0.f, bb = 0.f;
        #pragma unroll
        for (int ww = 0; ww < 8; ++ww) {
            a  += redA[ww * 256 + t];
            bb += redB[ww * 256 + t];
        }
        atomicAdd(&sums[t], a);
        atomicAdd(&sums[256 + t], bb);
    }
}

// ---------------------------------------------------------------------------
// S via abs-split: S_i = 0.505*lin + 0.495*SUM|x| + (32-rd)*lrelu(d),
// lin = rd*ap + a*EQ.  Inner loop: 2 VALU per 4-col visit.  Fused agg GEMM.
// ---------------------------------------------------------------------------
__global__ __launch_bounds__(256) void s_agg_kernel(
    const u16* __restrict__ PQb, const float* __restrict__ edges,
    const float* __restrict__ EQf, const float* __restrict__ sums,
    const float* __restrict__ gamma, const float* __restrict__ beta,
    const float* __restrict__ b1,
    const u16* __restrict__ W2b, const float* __restrict__ b2,
    u16* __restrict__ aggb)
{
    __shared__ float Qls[33 * 256];               // 33 KB a-scaled Q (row32=0)
    __shared__ u16 Ssb[16 * 256];                 // 8 KB, row-XOR swizzled
    __shared__ __align__(16) unsigned char list8[16 * 32];
    __shared__ int n1s[16];

    const int b    = blockIdx.x;
    const int i0   = blockIdx.y * 16;
    const int t    = threadIdx.x;
    const int lane = t & 63;
    const int w    = t >> 6;
    const int lr   = lane & 15;
    const int lk   = (lane >> 4) * 8;
    const int c0   = lane * 4;

    // BN1 coefficients from analytic sums
    const float Etot = sums[512];
    const float nz   = (float)NPAIR - Etot;
    const float invN = 1.f / (float)NPAIR;
    const f32x4 s1  = *(const f32x4*)(sums + c0);
    const f32x4 s2  = *(const f32x4*)(sums + 256 + c0);
    const f32x4 g4  = *(const f32x4*)(gamma + c0);
    const f32x4 be4 = *(const f32x4*)(beta + c0);
    const f32x4 b14 = *(const f32x4*)(b1 + c0);
    f32x4 a4, d4, ld4;
    #pragma unroll
    for (int k = 0; k < 4; ++k) {
        const float mean = (s1[k] + nz * b14[k]) * invN;
        const float ms   = (s2[k] + nz * b14[k] * b14[k]) * invN;
        const float var  = fmaf(-mean, mean, ms);
        a4[k]  = g4[k] * rsqrtf(var + BN_EPS);
        d4[k]  = fmaf(b14[k] - mean, a4[k], be4[k]);
        ld4[k] = fmaxf(d4[k], 0.01f * d4[k]);
    }

    // stage a-scaled Q (f32)
    #pragma unroll
    for (int it = 0; it < 8; ++it) {
        const int row = w + it * 4;
        const u16x4 qu = *(const u16x4*)(PQb + (size_t)(b * 32 + row) * 512 + 256 + c0);
        f32x4 q;
        #pragma unroll
        for (int k = 0; k < 4; ++k) q[k] = a4[k] * bf2f(qu[k]);
        *(f32x4*)&Qls[row * 256 + c0] = q;
    }
    if (t < 64) { const f32x4 z = {}; *(f32x4*)&Qls[32 * 256 + t * 4] = z; }
    if (t < 128) ((u32*)list8)[t] = 0x20202020u;

    const int il_t = t >> 5;
    const int j_t  = t & 31;
    const float ev0 = edges[(size_t)b * 1024 + (i0 + il_t) * 32 + j_t];
    const float ev1 = edges[(size_t)b * 1024 + (i0 + 8 + il_t) * 32 + j_t];
    __syncthreads();

    {
        const unsigned long long bal0 = __ballot(ev0 != 0.f);
        const u32 m0 = (lane < 32) ? (u32)bal0 : (u32)(bal0 >> 32);
        if (ev0 != 0.f)
            list8[il_t * 32 + __popc(m0 & ((1u << j_t) - 1u))] = (unsigned char)j_t;
        if (j_t == 0) n1s[il_t] = __popc(m0);
        const unsigned long long bal1 = __ballot(ev1 != 0.f);
        const u32 m1 = (lane < 32) ? (u32)bal1 : (u32)(bal1 >> 32);
        if (ev1 != 0.f)
            list8[(8 + il_t) * 32 + __popc(m1 & ((1u << j_t) - 1u))] = (unsigned char)j_t;
        if (j_t == 0) n1s[8 + il_t] = __popc(m1);
    }
    __syncthreads();

    #pragma unroll
    for (int ii = 0; ii < 4; ++ii) {
        const int il = 4 * w + ii;
        const int gi = b * 32 + i0 + il;
        const int n1 = n1s[il];
        const int npad = (n1 + 3) & ~3;
        const float frd = (float)n1;
        const float fz = (float)(32 - n1);
        const float fp = (float)(npad - n1);
        const u16x4 pu = *(const u16x4*)(PQb + (size_t)gi * 512 + c0);
        const f32x4 eq4 = *(const f32x4*)(EQf + (size_t)gi * 256 + c0);
        f32x4 ap, absacc;
        #pragma unroll
        for (int k = 0; k < 4; ++k) {
            ap[k] = fmaf(a4[k], bf2f(pu[k]), d4[k]);
            absacc[k] = -fp * fabsf(ap[k]);      // pad correction
        }
        const u32x4 l0 = *(const u32x4*)(list8 + il * 32);
        const u32x4 l1 = *(const u32x4*)(list8 + il * 32 + 16);
        const u32 wbuf[8] = {l0[0], l0[1], l0[2], l0[3], l1[0], l1[1], l1[2], l1[3]};
        #pragma unroll
        for (int wi = 0; wi < 8; ++wi) {
            if (wi * 4 >= npad) break;
            const u32 w4 = wbuf[wi];
            #pragma unroll
            for (int kb = 0; kb < 4; ++kb) {
                const int j = (w4 >> (kb * 8)) & 0xff;
                const f32x4 q = *(const f32x4*)&Qls[j * 256 + c0];
                #pragma unroll
                for (int k = 0; k < 4; ++k)
                    absacc[k] += fabsf(ap[k] + q[k]);
            }
        }
        u16x4 o;
        #pragma unroll
        for (int k = 0; k < 4; ++k) {
            const float lin = fmaf(frd, ap[k], a4[k] * eq4[k]);
            const float S = fmaf(fz, ld4[k], fmaf(0.505f, lin, 0.495f * absacc[k]));
            o[k] = f2bf(S);
        }
        const int off = (lane * 8) ^ ((il & 7) << 4);
        *(u16x4*)((char*)Ssb + il * 512 + off) = o;
    }
    __syncthreads();

    // agg tail: agg[16x128] = S @ w2^T + 32*b2
    const int colw = w * 32;
    f32x4 acc2[2] = {};
    #pragma unroll
    for (int ks = 0; ks < 8; ++ks) {
        const int rdoff = (ks * 64 + (lane >> 4) * 16) ^ ((lr & 7) << 4);
        const bf16x8 afr = *(const bf16x8*)((const char*)Ssb + lr * 512 + rdoff);
        #pragma unroll
        for (int cf = 0; cf < 2; ++cf) {
            const bf16x8 bfr = *(const bf16x8*)(W2b + (size_t)(colw + cf * 16 + lr) * 256 + ks * 32 + lk);
            acc2[cf] = __builtin_amdgcn_mfma_f32_16x16x32_bf16(afr, bfr, acc2[cf], 0, 0, 0);
        }
    }
    #pragma unroll
    for (int cf = 0; cf < 2; ++cf) {
        const int col = colw + cf * 16 + lr;
        const float bv = (float)NOBJ * b2[col];
        #pragma unroll
        for (int r = 0; r < 4; ++r) {
            const int rowl = (lane >> 4) * 4 + r;
            aggb[(size_t)(b * 32 + i0 + rowl) * 128 + col] = f2bf(acc2[cf][r] + bv);
        }
    }
}

// ---------------------------------------------------------------------------
// H2 = [Ab | aggb] @ fw1^T + fb1 (f32 out) + fused column stats.
// ---------------------------------------------------------------------------
__global__ __launch_bounds__(256) void h2_gemm(
    const u16* __restrict__ Ab, const u16* __restrict__ aggb,
    const u16* __restrict__ FW1b, const float* __restrict__ fb1,
    float* __restrict__ H2, float* __restrict__ sums2)
{
    __shared__ float sred[64];
    const int lane = threadIdx.x & 63;
    const int wave = threadIdx.x >> 6;
    const int row0 = blockIdx.y * 64 + wave * 16;
    const int col0 = blockIdx.x * 32;
    const int lr = lane & 15;
    const int lk = (lane >> 4) * 8;

    f32x4 acc[2] = {};
    #pragma unroll
    for (int ks = 0; ks < 8; ++ks) {
        const int kabs = ks * 32 + lk;
        const bf16x8 af = (kabs < 128)
            ? *(const bf16x8*)(Ab   + (size_t)(row0 + lr) * 128 + kabs)
            : *(const bf16x8*)(aggb + (size_t)(row0 + lr) * 128 + (kabs - 128));
        #pragma unroll
        for (int cf = 0; cf < 2; ++cf) {
            const bf16x8 bf = *(const bf16x8*)(FW1b + (size_t)(col0 + cf * 16 + lr) * 256 + kabs);
            acc[cf] = __builtin_amdgcn_mfma_f32_16x16x32_bf16(af, bf, acc[cf], 0, 0, 0);
        }
    }

    if (threadIdx.x < 64) sred[threadIdx.x] = 0.f;
    __syncthreads();
    #pragma unroll
    for (int cf = 0; cf < 2; ++cf) {
        const int col = col0 + cf * 16 + lr;
        const float bv = fb1[col];
        float s = 0.f, ss = 0.f;
        #pragma unroll
        for (int r = 0; r < 4; ++r) {
            const int row = row0 + (lane >> 4) * 4 + r;
            const float v = acc[cf][r] + bv;
            H2[(size_t)row * 256 + col] = v;
            s += v;
            ss = fmaf(v, v, ss);
        }
        atomicAdd(&sred[cf * 16 + lr], s);
        atomicAdd(&sred[32 + cf * 16 + lr], ss);
    }
    __syncthreads();
    if (threadIdx.x < 32) {
        atomicAdd(&sums2[col0 + threadIdx.x], sred[threadIdx.x]);
        atomicAdd(&sums2[256 + col0 + threadIdx.x], sred[32 + threadIdx.x]);
    }
}

// ---------------------------------------------------------------------------
// out = lrelu(bn(H2)) @ fw2^T + fb2, finalize2 computed in-block.
// ---------------------------------------------------------------------------
__global__ __launch_bounds__(256) void out_gemm(
    const float* __restrict__ H2, const u16* __restrict__ FW2b,
    const float* __restrict__ fb2, const float* __restrict__ sums2,
    const float* __restrict__ gamma, const float* __restrict__ beta,
    float* __restrict__ out)
{
    __shared__ float adl[512];
    const int t = threadIdx.x;
    {
        const float invN = 1.f / (float)R1;
        const float mean = sums2[t] * invN;
        const float var  = fmaf(-mean, mean, sums2[256 + t] * invN);
        const float a    = gamma[t] * rsqrtf(var + BN_EPS);
        adl[t]       = a;
        adl[256 + t] = fmaf(-mean, a, beta[t]);
    }
    __syncthreads();

    const int lane = t & 63;
    const int wave = t >> 6;
    const int row0 = blockIdx.y * 64 + wave * 16;
    const int col0 = blockIdx.x * 32;
    const int lr = lane & 15;
    const int lk = (lane >> 4) * 8;

    f32x4 acc[2] = {};
    #pragma unroll
    for (int ks = 0; ks < 8; ++ks) {
        const int kabs = ks * 32 + lk;
        const bf16x8 af = cvt8_bn(H2 + (size_t)(row0 + lr) * 256 + kabs,
                                  adl + kabs, adl + 256 + kabs);
        #pragma unroll
        for (int cf = 0; cf < 2; ++cf) {
            const bf16x8 bf = *(const bf16x8*)(FW2b + (size_t)(col0 + cf * 16 + lr) * 256 + kabs);
            acc[cf] = __builtin_amdgcn_mfma_f32_16x16x32_bf16(af, bf, acc[cf], 0, 0, 0);
        }
    }
    #pragma unroll
    for (int cf = 0; cf < 2; ++cf) {
        const int col = col0 + cf * 16 + lr;
        const float bv = fb2[col];
        #pragma unroll
        for (int r = 0; r < 4; ++r) {
            const int row = row0 + (lane >> 4) * 4 + r;
            out[(size_t)row * 128 + col] = acc[cf][r] + bv;
        }
    }
}

// ---------------------------------------------------------------------------
extern "C" void kernel_launch(void* const* d_in, const int* in_sizes, int n_in,
                              void* d_out, int out_size, void* d_ws, size_t ws_size,
                              hipStream_t stream)
{
    const float* state     = (const float*)d_in[0];
    const float* edges     = (const float*)d_in[1];
    const float* msg_w1    = (const float*)d_in[2];
    const float* msg_b1    = (const float*)d_in[3];
    const float* msg_gamma = (const float*)d_in[4];
    const float* msg_beta  = (const float*)d_in[5];
    const float* msg_w2    = (const float*)d_in[6];
    const float* msg_b2    = (const float*)d_in[7];
    const float* fin_w1    = (const float*)d_in[8];
    const float* fin_b1    = (const float*)d_in[9];
    const float* fin_gamma = (const float*)d_in[10];
    const float* fin_beta  = (const float*)d_in[11];
    const float* fin_w2    = (const float*)d_in[12];
    const float* fin_b2    = (const float*)d_in[13];

    char* w = (char*)d_ws;
    u16*   PQb  = (u16*)(w);                // 8192x512 bf16  ( 8 MB)
    u16*   Ab   = (u16*)(w + 8388608);      // 8192x128 bf16  ( 2 MB)
    u16*   aggb = (u16*)(w + 10485760);     // 8192x128 bf16  ( 2 MB)
    float* H2   = (float*)(w + 12582912);   // 8192x256 f32   ( 8 MB)
    float* EQf  = (float*)(w + 20971520);   // 8192x256 f32   ( 8 MB)
    u16*   W1b  = (u16*)(w + 29360128);     // 512x128 bf16
    u16*   W2b  = (u16*)(w + 29491200);     // 128x256 bf16
    u16*   FW1b = (u16*)(w + 29556736);     // 256x256 bf16
    u16*   FW2b = (u16*)(w + 29687808);     // 128x256 bf16
    float* sums = (float*)(w + 29753344);   // sums1(512)+E(1)+pad, sums2 at +544
    float* sums2 = sums + 544;

    prep_kernel<<<195, 256, 0, stream>>>(
        msg_w1, (const float4*)msg_w2, (const float4*)fin_w1, (const float4*)fin_w2,
        (u16x4*)W1b, (u16x4*)W2b, (u16x4*)FW1b, (u16x4*)FW2b, (f32x4*)sums);

    pq_stats<<<256, 512, 0, stream>>>(state, W1b, edges, msg_b1,
                                      PQb, Ab, EQf, sums);

    s_agg_kernel<<<dim3(256, 2), 256, 0, stream>>>(
        PQb, edges, EQf, sums, msg_gamma, msg_beta, msg_b1, W2b, msg_b2, aggb);

    h2_gemm<<<dim3(8, 128), 256, 0, stream>>>(Ab, aggb, FW1b, fin_b1, H2, sums2);

    out_gemm<<<dim3(4, 128), 256, 0, stream>>>(
        H2, FW2b, fin_b2, sums2, fin_gamma, fin_beta, (float*)d_out);
}

// Round 7
// 69.095 us; speedup vs baseline: 1.5746x; 1.0042x over previous
//
#include <hip/hip_runtime.h>

#define NOBJ   32
#define DIM    128
#define HW     256
#define R1     8192
#define NPAIR  262144
#define BN_EPS 1e-5f

typedef unsigned short u16;
typedef unsigned int   u32;
typedef __attribute__((ext_vector_type(8))) short bf16x8;
typedef __attribute__((ext_vector_type(4))) float f32x4;
typedef __attribute__((ext_vector_type(4))) unsigned short u16x4;
typedef __attribute__((ext_vector_type(4))) unsigned int u32x4;

__device__ __forceinline__ u16 f2bf(float f) {
    union { float f; unsigned u; } v; v.f = f;
    unsigned r = v.u + 0x7fffu + ((v.u >> 16) & 1u);
    return (u16)(r >> 16);
}
__device__ __forceinline__ float bf2f(u16 u) {
    union { unsigned u; float f; } v; v.u = ((unsigned)u) << 16; return v.f;
}
__device__ __forceinline__ u16x4 cvt4(float4 v) {
    u16x4 r;
    r[0] = f2bf(v.x); r[1] = f2bf(v.y); r[2] = f2bf(v.z); r[3] = f2bf(v.w);
    return r;
}
__device__ __forceinline__ bf16x8 cvt8_f32(const float* p) {
    f32x4 v0 = *(const f32x4*)p, v1 = *(const f32x4*)(p + 4);
    bf16x8 r;
    #pragma unroll
    for (int k = 0; k < 4; ++k) {
        r[k]     = (short)f2bf(v0[k]);
        r[4 + k] = (short)f2bf(v1[k]);
    }
    return r;
}
// bf16 input + BN + lrelu + back to bf16 fragment
__device__ __forceinline__ bf16x8 cvt8_bn_b(const u16* p, const float* a, const float* d) {
    u16x4 v0 = *(const u16x4*)p, v1 = *(const u16x4*)(p + 4);
    f32x4 a0 = *(const f32x4*)a, a1 = *(const f32x4*)(a + 4);
    f32x4 d0 = *(const f32x4*)d, d1 = *(const f32x4*)(d + 4);
    bf16x8 r;
    #pragma unroll
    for (int k = 0; k < 4; ++k) {
        float x0 = fmaf(a0[k], bf2f(v0[k]), d0[k]); x0 = fmaxf(x0, 0.01f * x0);
        float x1 = fmaf(a1[k], bf2f(v1[k]), d1[k]); x1 = fmaxf(x1, 0.01f * x1);
        r[k]     = (short)f2bf(x0);
        r[4 + k] = (short)f2bf(x1);
    }
    return r;
}

// ---------------------------------------------------------------------------
// prep: weights fp32->bf16 (W1b remapped [512][128]) + zero sums region.
// ---------------------------------------------------------------------------
__global__ __launch_bounds__(256) void prep_kernel(
    const float* __restrict__ w1, const float4* __restrict__ w2,
    const float4* __restrict__ fw1, const float4* __restrict__ fw2,
    u16x4* __restrict__ W1b, u16x4* __restrict__ W2b,
    u16x4* __restrict__ FW1b, u16x4* __restrict__ FW2b,
    f32x4* __restrict__ sums)
{
    int g = blockIdx.x * 256 + threadIdx.x;
    if (g < 16384) {
        const int o = g * 4, n = o >> 7, k = o & 127;
        const float4 v = *(const float4*)(w1 + (n < 256 ? n * 256 + k
                                                        : (n - 256) * 256 + 128 + k));
        W1b[g] = cvt4(v); return;
    }
    g -= 16384;
    if (g < 8192) { W2b[g] = cvt4(w2[g]); return; }
    g -= 8192;
    if (g < 16384) { FW1b[g] = cvt4(fw1[g]); return; }
    g -= 16384;
    if (g < 8192) { FW2b[g] = cvt4(fw2[g]); return; }
    g -= 8192;
    if (g < 264) { const f32x4 z = {}; sums[g] = z; }
}

// ---------------------------------------------------------------------------
// Per-batch fused kernel, 1024 threads (16 waves):
//   PQ[32x512] = state @ [w1a|w1b]^T (MFMA, 32 cols/wave) -> PQb bf16 (+Ab)
//   EQ_i = sum_{j:e=1} Q_j -> EQf ;  analytic BN1 moments -> sums
// ---------------------------------------------------------------------------
__global__ __launch_bounds__(1024) void pq_stats(
    const float* __restrict__ state, const u16* __restrict__ W1b,
    const float* __restrict__ edges, const float* __restrict__ b1,
    u16* __restrict__ PQb, u16* __restrict__ Ab, float* __restrict__ EQf,
    float* __restrict__ sums)
{
    __shared__ float Qls[33 * 256];                 // 33 KB rounded Q (row32=0)
    __shared__ float redA[16 * 256];                // 16 KB
    __shared__ float redB[16 * 256];                // 16 KB
    __shared__ u32 masks[32];
    __shared__ __align__(16) unsigned char list8[32 * 32];
    __shared__ float cdf[32];

    const int b    = blockIdx.x;
    const int t    = threadIdx.x;
    const int lane = t & 63;
    const int w    = t >> 6;       // 0..15
    const int lr   = lane & 15;
    const int lk   = (lane >> 4) * 8;
    const int c0   = lane * 4;

    if (t < 256) ((u32*)list8)[t] = 0x20202020u;    // pad sentinel j=32
    if (t < 64) { const f32x4 z = {}; *(f32x4*)&Qls[32 * 256 + t * 4] = z; }

    // one edge per thread (t = il*32 + j)
    const float ev = edges[(size_t)b * 1024 + t];

    // ---- GEMM: wave w covers cols w*32..w*32+31 ----
    const int col0 = w * 32;
    f32x4 acc[2][2] = {};
    #pragma unroll
    for (int ks = 0; ks < 4; ++ks) {
        const int kabs = ks * 32 + lk;
        bf16x8 af[2];
        #pragma unroll
        for (int rf = 0; rf < 2; ++rf)
            af[rf] = cvt8_f32(state + (size_t)(b * 32 + rf * 16 + lr) * 128 + kabs);
        if (w == 0) {
            #pragma unroll
            for (int rf = 0; rf < 2; ++rf)
                *(bf16x8*)(Ab + (size_t)(b * 32 + rf * 16 + lr) * 128 + kabs) = af[rf];
        }
        #pragma unroll
        for (int cf = 0; cf < 2; ++cf) {
            const bf16x8 bf = *(const bf16x8*)(W1b + (size_t)(col0 + cf * 16 + lr) * 128 + kabs);
            #pragma unroll
            for (int rf = 0; rf < 2; ++rf)
                acc[rf][cf] = __builtin_amdgcn_mfma_f32_16x16x32_bf16(af[rf], bf, acc[rf][cf], 0, 0, 0);
        }
    }
    #pragma unroll
    for (int rf = 0; rf < 2; ++rf)
        #pragma unroll
        for (int cf = 0; cf < 2; ++cf) {
            const int col = col0 + cf * 16 + lr;
            #pragma unroll
            for (int r = 0; r < 4; ++r) {
                const int row = rf * 16 + (lane >> 4) * 4 + r;
                const u16 u = f2bf(acc[rf][cf][r]);
                PQb[(size_t)(b * 32 + row) * 512 + col] = u;
                if (col >= 256) Qls[row * 256 + (col - 256)] = bf2f(u);
            }
        }
    __syncthreads();   // S1: staging + inits visible

    // ---- masks + compacted lists (per-wave ballot: lanes<32 row 2w, else 2w+1) ----
    {
        const int il_t = t >> 5;
        const int j_t  = t & 31;
        const unsigned long long bal = __ballot(ev != 0.f);
        const u32 m32 = (lane < 32) ? (u32)bal : (u32)(bal >> 32);
        if (ev != 0.f)
            list8[il_t * 32 + __popc(m32 & ((1u << j_t) - 1u))] = (unsigned char)j_t;
        if (j_t == 0) masks[il_t] = m32;
    }
    __syncthreads();   // S2: masks + lists ready

    if (t < 32) {
        u32 cnt = 0;
        #pragma unroll
        for (int i = 0; i < 32; ++i) cnt += (masks[i] >> t) & 1u;
        cdf[t] = (float)cnt;
    }
    if (t == 0) {
        int tot = 0;
        #pragma unroll
        for (int i = 0; i < 32; ++i) tot += __popc(masks[i]);
        atomicAdd(&sums[512], (float)tot);
    }

    const f32x4 b14 = *(const f32x4*)(b1 + c0);
    f32x4 sumA = {}, sumB = {};

    // ---- EQ + row-terms: wave w owns rows 2w, 2w+1 ----
    #pragma unroll
    for (int ii = 0; ii < 2; ++ii) {
        const int il = 2 * w + ii;
        const int n1 = __popc(masks[il]);
        const int npad = (n1 + 3) & ~3;
        const float frd = (float)n1;
        f32x4 eq = {};
        const u32x4 l0 = *(const u32x4*)(list8 + il * 32);
        const u32x4 l1 = *(const u32x4*)(list8 + il * 32 + 16);
        const u32 wbuf[8] = {l0[0], l0[1], l0[2], l0[3], l1[0], l1[1], l1[2], l1[3]};
        #pragma unroll
        for (int wi = 0; wi < 8; ++wi) {
            if (wi * 4 >= npad) break;
            const u32 w4 = wbuf[wi];
            #pragma unroll
            for (int kb = 0; kb < 4; ++kb) {
                const int j = (w4 >> (kb * 8)) & 0xff;          // pads -> row 32 (zero)
                const f32x4 q = *(const f32x4*)&Qls[j * 256 + c0];
                #pragma unroll
                for (int k = 0; k < 4; ++k) eq[k] += q[k];
            }
        }
        *(f32x4*)(EQf + (size_t)(b * 32 + il) * 256 + c0) = eq;
        // P from PQb (written by this block; L2-hot)
        const u16x4 pu = *(const u16x4*)(PQb + (size_t)(b * 32 + il) * 512 + c0);
        #pragma unroll
        for (int k = 0; k < 4; ++k) {
            const float pb = bf2f(pu[k]) + b14[k];
            sumA[k] += frd * pb + eq[k];
            sumB[k] = fmaf(frd * pb + 2.f * eq[k], pb, sumB[k]);
        }
    }
    __syncthreads();   // S3: cdf ready

    // ---- coldeg-weighted Q^2: wave w uses j = 2w, 2w+1 ----
    #pragma unroll
    for (int jj = 0; jj < 2; ++jj) {
        const int j = 2 * w + jj;
        const float cdj = cdf[j];
        const f32x4 q = *(const f32x4*)&Qls[j * 256 + c0];
        #pragma unroll
        for (int k = 0; k < 4; ++k) sumB[k] = fmaf(cdj * q[k], q[k], sumB[k]);
    }
    *(f32x4*)&redA[w * 256 + c0] = sumA;
    *(f32x4*)&redB[w * 256 + c0] = sumB;
    __syncthreads();   // S4
    if (t < 256) {
        float a = 0.f, bb = 0.f;
        #pragma unroll
        for (int ww = 0; ww < 16; ++ww) {
            a  += redA[ww * 256 + t];
            bb += redB[ww * 256 + t];
        }
        atomicAdd(&sums[t], a);
        atomicAdd(&sums[256 + t], bb);
    }
}

// ---------------------------------------------------------------------------
// S via abs-split + fused agg GEMM; 512 threads (8 waves), 16 rows/block.
// ---------------------------------------------------------------------------
__global__ __launch_bounds__(512) void s_agg_kernel(
    const u16* __restrict__ PQb, const float* __restrict__ edges,
    const float* __restrict__ EQf, const float* __restrict__ sums,
    const float* __restrict__ gamma, const float* __restrict__ beta,
    const float* __restrict__ b1,
    const u16* __restrict__ W2b, const float* __restrict__ b2,
    u16* __restrict__ aggb)
{
    __shared__ float Qls[33 * 256];               // 33 KB a-scaled Q (row32=0)
    __shared__ u16 Ssb[16 * 256];                 // 8 KB, row-XOR swizzled
    __shared__ __align__(16) unsigned char list8[16 * 32];
    __shared__ int n1s[16];

    const int b    = blockIdx.x;
    const int i0   = blockIdx.y * 16;
    const int t    = threadIdx.x;
    const int lane = t & 63;
    const int w    = t >> 6;      // 0..7
    const int lr   = lane & 15;
    const int lk   = (lane >> 4) * 8;
    const int c0   = lane * 4;

    // BN1 coefficients from analytic sums
    const float Etot = sums[512];
    const float nz   = (float)NPAIR - Etot;
    const float invN = 1.f / (float)NPAIR;
    const f32x4 s1  = *(const f32x4*)(sums + c0);
    const f32x4 s2  = *(const f32x4*)(sums + 256 + c0);
    const f32x4 g4  = *(const f32x4*)(gamma + c0);
    const f32x4 be4 = *(const f32x4*)(beta + c0);
    const f32x4 b14 = *(const f32x4*)(b1 + c0);
    f32x4 a4, d4, ld4;
    #pragma unroll
    for (int k = 0; k < 4; ++k) {
        const float mean = (s1[k] + nz * b14[k]) * invN;
        const float ms   = (s2[k] + nz * b14[k] * b14[k]) * invN;
        const float var  = fmaf(-mean, mean, ms);
        a4[k]  = g4[k] * rsqrtf(var + BN_EPS);
        d4[k]  = fmaf(b14[k] - mean, a4[k], be4[k]);
        ld4[k] = fmaxf(d4[k], 0.01f * d4[k]);
    }

    // stage a-scaled Q (f32): 8 waves x 4 iters = 32 rows
    #pragma unroll
    for (int it = 0; it < 4; ++it) {
        const int row = w + it * 8;
        const u16x4 qu = *(const u16x4*)(PQb + (size_t)(b * 32 + row) * 512 + 256 + c0);
        f32x4 q;
        #pragma unroll
        for (int k = 0; k < 4; ++k) q[k] = a4[k] * bf2f(qu[k]);
        *(f32x4*)&Qls[row * 256 + c0] = q;
    }
    if (t < 64) { const f32x4 z = {}; *(f32x4*)&Qls[32 * 256 + t * 4] = z; }
    if (t < 128) ((u32*)list8)[t] = 0x20202020u;

    // one edge per thread: rows i0..i0+15
    const float ev = edges[(size_t)b * 1024 + (i0 + (t >> 5)) * 32 + (t & 31)];
    __syncthreads();

    {
        const int il_t = t >> 5;
        const int j_t  = t & 31;
        const unsigned long long bal = __ballot(ev != 0.f);
        const u32 m32 = (lane < 32) ? (u32)bal : (u32)(bal >> 32);
        if (ev != 0.f)
            list8[il_t * 32 + __popc(m32 & ((1u << j_t) - 1u))] = (unsigned char)j_t;
        if (j_t == 0) n1s[il_t] = __popc(m32);
    }
    __syncthreads();

    #pragma unroll
    for (int ii = 0; ii < 2; ++ii) {
        const int il = 2 * w + ii;
        const int gi = b * 32 + i0 + il;
        const int n1 = n1s[il];
        const int npad = (n1 + 3) & ~3;
        const float frd = (float)n1;
        const float fz = (float)(32 - n1);
        const float fp = (float)(npad - n1);
        const u16x4 pu = *(const u16x4*)(PQb + (size_t)gi * 512 + c0);
        const f32x4 eq4 = *(const f32x4*)(EQf + (size_t)gi * 256 + c0);
        f32x4 ap, absacc;
        #pragma unroll
        for (int k = 0; k < 4; ++k) {
            ap[k] = fmaf(a4[k], bf2f(pu[k]), d4[k]);
            absacc[k] = -fp * fabsf(ap[k]);      // pad correction
        }
        const u32x4 l0 = *(const u32x4*)(list8 + il * 32);
        const u32x4 l1 = *(const u32x4*)(list8 + il * 32 + 16);
        const u32 wbuf[8] = {l0[0], l0[1], l0[2], l0[3], l1[0], l1[1], l1[2], l1[3]};
        #pragma unroll
        for (int wi = 0; wi < 8; ++wi) {
            if (wi * 4 >= npad) break;
            const u32 w4 = wbuf[wi];
            #pragma unroll
            for (int kb = 0; kb < 4; ++kb) {
                const int j = (w4 >> (kb * 8)) & 0xff;
                const f32x4 q = *(const f32x4*)&Qls[j * 256 + c0];
                #pragma unroll
                for (int k = 0; k < 4; ++k)
                    absacc[k] += fabsf(ap[k] + q[k]);
            }
        }
        u16x4 o;
        #pragma unroll
        for (int k = 0; k < 4; ++k) {
            const float lin = fmaf(frd, ap[k], a4[k] * eq4[k]);
            const float S = fmaf(fz, ld4[k], fmaf(0.505f, lin, 0.495f * absacc[k]));
            o[k] = f2bf(S);
        }
        const int off = (lane * 8) ^ ((il & 7) << 4);
        *(u16x4*)((char*)Ssb + il * 512 + off) = o;
    }
    __syncthreads();

    // agg tail: agg[16x128] = S @ w2^T + 32*b2 ; wave w covers 16 cols
    const int colw = w * 16;
    f32x4 acc2 = {};
    #pragma unroll
    for (int ks = 0; ks < 8; ++ks) {
        const int rdoff = (ks * 64 + (lane >> 4) * 16) ^ ((lr & 7) << 4);
        const bf16x8 afr = *(const bf16x8*)((const char*)Ssb + lr * 512 + rdoff);
        const bf16x8 bfr = *(const bf16x8*)(W2b + (size_t)(colw + lr) * 256 + ks * 32 + lk);
        acc2 = __builtin_amdgcn_mfma_f32_16x16x32_bf16(afr, bfr, acc2, 0, 0, 0);
    }
    {
        const int col = colw + lr;
        const float bv = (float)NOBJ * b2[col];
        #pragma unroll
        for (int r = 0; r < 4; ++r) {
            const int rowl = (lane >> 4) * 4 + r;
            aggb[(size_t)(b * 32 + i0 + rowl) * 128 + col] = f2bf(acc2[r] + bv);
        }
    }
}

// ---------------------------------------------------------------------------
// H2 = [Ab | aggb] @ fw1^T + fb1 -> bf16 + fused column stats (f32 pre-round).
// ---------------------------------------------------------------------------
__global__ __launch_bounds__(256) void h2_gemm(
    const u16* __restrict__ Ab, const u16* __restrict__ aggb,
    const u16* __restrict__ FW1b, const float* __restrict__ fb1,
    u16* __restrict__ H2b, float* __restrict__ sums2)
{
    __shared__ float sred[64];
    const int lane = threadIdx.x & 63;
    const int wave = threadIdx.x >> 6;
    const int row0 = blockIdx.y * 64 + wave * 16;
    const int col0 = blockIdx.x * 32;
    const int lr = lane & 15;
    const int lk = (lane >> 4) * 8;

    f32x4 acc[2] = {};
    #pragma unroll
    for (int ks = 0; ks < 8; ++ks) {
        const int kabs = ks * 32 + lk;
        const bf16x8 af = (kabs < 128)
            ? *(const bf16x8*)(Ab   + (size_t)(row0 + lr) * 128 + kabs)
            : *(const bf16x8*)(aggb + (size_t)(row0 + lr) * 128 + (kabs - 128));
        #pragma unroll
        for (int cf = 0; cf < 2; ++cf) {
            const bf16x8 bf = *(const bf16x8*)(FW1b + (size_t)(col0 + cf * 16 + lr) * 256 + kabs);
            acc[cf] = __builtin_amdgcn_mfma_f32_16x16x32_bf16(af, bf, acc[cf], 0, 0, 0);
        }
    }

    if (threadIdx.x < 64) sred[threadIdx.x] = 0.f;
    __syncthreads();
    #pragma unroll
    for (int cf = 0; cf < 2; ++cf) {
        const int col = col0 + cf * 16 + lr;
        const float bv = fb1[col];
        float s = 0.f, ss = 0.f;
        #pragma unroll
        for (int r = 0; r < 4; ++r) {
            const int row = row0 + (lane >> 4) * 4 + r;
            const float v = acc[cf][r] + bv;
            H2b[(size_t)row * 256 + col] = f2bf(v);
            s += v;
            ss = fmaf(v, v, ss);
        }
        atomicAdd(&sred[cf * 16 + lr], s);
        atomicAdd(&sred[32 + cf * 16 + lr], ss);
    }
    __syncthreads();
    if (threadIdx.x < 32) {
        atomicAdd(&sums2[col0 + threadIdx.x], sred[threadIdx.x]);
        atomicAdd(&sums2[256 + col0 + threadIdx.x], sred[32 + threadIdx.x]);
    }
}

// ---------------------------------------------------------------------------
// out = lrelu(bn(H2b)) @ fw2^T + fb2, finalize2 computed in-block.
// ---------------------------------------------------------------------------
__global__ __launch_bounds__(256) void out_gemm(
    const u16* __restrict__ H2b, const u16* __restrict__ FW2b,
    const float* __restrict__ fb2, const float* __restrict__ sums2,
    const float* __restrict__ gamma, const float* __restrict__ beta,
    float* __restrict__ out)
{
    __shared__ float adl[512];
    const int t = threadIdx.x;
    {
        const float invN = 1.f / (float)R1;
        const float mean = sums2[t] * invN;
        const float var  = fmaf(-mean, mean, sums2[256 + t] * invN);
        const float a    = gamma[t] * rsqrtf(var + BN_EPS);
        adl[t]       = a;
        adl[256 + t] = fmaf(-mean, a, beta[t]);
    }
    __syncthreads();

    const int lane = t & 63;
    const int wave = t >> 6;
    const int row0 = blockIdx.y * 64 + wave * 16;
    const int col0 = blockIdx.x * 32;
    const int lr = lane & 15;
    const int lk = (lane >> 4) * 8;

    f32x4 acc[2] = {};
    #pragma unroll
    for (int ks = 0; ks < 8; ++ks) {
        const int kabs = ks * 32 + lk;
        const bf16x8 af = cvt8_bn_b(H2b + (size_t)(row0 + lr) * 256 + kabs,
                                    adl + kabs, adl + 256 + kabs);
        #pragma unroll
        for (int cf = 0; cf < 2; ++cf) {
            const bf16x8 bf = *(const bf16x8*)(FW2b + (size_t)(col0 + cf * 16 + lr) * 256 + kabs);
            acc[cf] = __builtin_amdgcn_mfma_f32_16x16x32_bf16(af, bf, acc[cf], 0, 0, 0);
        }
    }
    #pragma unroll
    for (int cf = 0; cf < 2; ++cf) {
        const int col = col0 + cf * 16 + lr;
        const float bv = fb2[col];
        #pragma unroll
        for (int r = 0; r < 4; ++r) {
            const int row = row0 + (lane >> 4) * 4 + r;
            out[(size_t)row * 128 + col] = acc[cf][r] + bv;
        }
    }
}

// ---------------------------------------------------------------------------
extern "C" void kernel_launch(void* const* d_in, const int* in_sizes, int n_in,
                              void* d_out, int out_size, void* d_ws, size_t ws_size,
                              hipStream_t stream)
{
    const float* state     = (const float*)d_in[0];
    const float* edges     = (const float*)d_in[1];
    const float* msg_w1    = (const float*)d_in[2];
    const float* msg_b1    = (const float*)d_in[3];
    const float* msg_gamma = (const float*)d_in[4];
    const float* msg_beta  = (const float*)d_in[5];
    const float* msg_w2    = (const float*)d_in[6];
    const float* msg_b2    = (const float*)d_in[7];
    const float* fin_w1    = (const float*)d_in[8];
    const float* fin_b1    = (const float*)d_in[9];
    const float* fin_gamma = (const float*)d_in[10];
    const float* fin_beta  = (const float*)d_in[11];
    const float* fin_w2    = (const float*)d_in[12];
    const float* fin_b2    = (const float*)d_in[13];

    char* w = (char*)d_ws;
    u16*   PQb  = (u16*)(w);                // 8192x512 bf16  ( 8 MB)
    u16*   Ab   = (u16*)(w + 8388608);      // 8192x128 bf16  ( 2 MB)
    u16*   aggb = (u16*)(w + 10485760);     // 8192x128 bf16  ( 2 MB)
    u16*   H2b  = (u16*)(w + 12582912);     // 8192x256 bf16  ( 4 MB)
    float* EQf  = (float*)(w + 16777216);   // 8192x256 f32   ( 8 MB)
    u16*   W1b  = (u16*)(w + 25165824);     // 512x128 bf16
    u16*   W2b  = (u16*)(w + 25296896);     // 128x256 bf16
    u16*   FW1b = (u16*)(w + 25362432);     // 256x256 bf16
    u16*   FW2b = (u16*)(w + 25493504);     // 128x256 bf16
    float* sums = (float*)(w + 25559040);   // sums1(512)+E(1)+pad(31)+sums2(512)
    float* sums2 = sums + 544;

    prep_kernel<<<195, 256, 0, stream>>>(
        msg_w1, (const float4*)msg_w2, (const float4*)fin_w1, (const float4*)fin_w2,
        (u16x4*)W1b, (u16x4*)W2b, (u16x4*)FW1b, (u16x4*)FW2b, (f32x4*)sums);

    pq_stats<<<256, 1024, 0, stream>>>(state, W1b, edges, msg_b1,
                                       PQb, Ab, EQf, sums);

    s_agg_kernel<<<dim3(256, 2), 512, 0, stream>>>(
        PQb, edges, EQf, sums, msg_gamma, msg_beta, msg_b1, W2b, msg_b2, aggb);

    h2_gemm<<<dim3(8, 128), 256, 0, stream>>>(Ab, aggb, FW1b, fin_b1, H2b, sums2);

    out_gemm<<<dim3(4, 128), 256, 0, stream>>>(
        H2b, FW2b, fin_b2, sums2, fin_gamma, fin_beta, (float*)d_out);
}